// Round 2
// baseline (307.720 us; speedup 1.0000x reference)
//
#include <hip/hip_runtime.h>
#include <hip/hip_bf16.h>
#include <stdint.h>

#define IN_F 1024
#define OUT_F 1024
#define NB 8
#define KDIM (IN_F + IN_F * NB)  /* 9216 */
#define NROWS 4096
#define SLICE_ELEMS (NROWS * OUT_F)

typedef __attribute__((ext_vector_type(8))) short bf16x8;
typedef __attribute__((ext_vector_type(4))) short bf16x4;
typedef __attribute__((ext_vector_type(4))) float f32x4;

// Closed-form uniform cubic B-spline, equivalent to the reference Cox-de Boor
// recursion (knots t_j = -2.2 + 0.4j uniform, EPS=1e-8 perturbs denoms by ~1e-8,
// far below bf16 rounding). For x in [t_i, t_{i+1}), the 4 nonzero bases are the
// standard cardinal cubic polynomials of f = (x-t_i)/h; outputs j = i-3..i.
__device__ __forceinline__ void bspline8(float x, float b8[8]) {
  float u = (x + 2.2f) * 2.5f;  // (x - t0)/h
  bool in = (u >= 0.0f) && (u < 11.0f);
  float uc = fminf(fmaxf(u, 0.0f), 10.99f);
  int i = (int)uc;
  float f = uc - (float)i;
  float g = 1.0f - f;
  float f2 = f * f, f3 = f2 * f;
  const float s = 1.0f / 6.0f;
  float v0 = f3 * s;                                    // j = i   (d=0)
  float v1 = (-3.0f * f3 + 3.0f * f2 + 3.0f * f + 1.0f) * s;  // j = i-1
  float v2 = (3.0f * f3 - 6.0f * f2 + 4.0f) * s;        // j = i-2
  float v3 = g * g * g * s;                             // j = i-3 (d=3)
#pragma unroll
  for (int j = 0; j < 8; ++j) {
    int d = i - j;
    float r = (d == 0) ? v0 : (d == 1) ? v1 : (d == 2) ? v2 : (d == 3) ? v3 : 0.0f;
    b8[j] = in ? r : 0.0f;
  }
}

// A[n, 0:1024] = silu(x[n,:]);  A[n, 1024 + i*8 + b] = basis_b(x[n,i]).  bf16 out.
__global__ void prep_kernel(const float* __restrict__ x, __hip_bfloat16* __restrict__ A) {
  int idx = blockIdx.x * 256 + threadIdx.x;  // 4096*1024 threads
  int n = idx >> 10;
  int i = idx & 1023;
  float xv = x[idx];
  float sl = xv / (1.0f + __expf(-xv));
  __hip_bfloat16* row = A + (size_t)n * KDIM;
  row[i] = __float2bfloat16(sl);
  float b8[8];
  bspline8(xv, b8);
  alignas(16) __hip_bfloat16 tmp[8];
#pragma unroll
  for (int c = 0; c < 8; ++c) tmp[c] = __float2bfloat16(b8[c]);
  *(bf16x8*)(row + IN_F + i * 8) = *(const bf16x8*)tmp;  // 16B coalesced store
}

// W[o, 0:1024] = base_weight[o,:]; W[o, 1024:] = spline_weight flat. 4 elems/thread.
__global__ void wconv_kernel(const float* __restrict__ bw, const float* __restrict__ sw,
                             __hip_bfloat16* __restrict__ W) {
  int v = blockIdx.x * 256 + threadIdx.x;  // (1024*9216)/4 threads
  int e = v * 4;
  int o = e / KDIM;
  int k = e - o * KDIM;
  float4 val = (k < IN_F) ? *(const float4*)(bw + o * IN_F + k)
                          : *(const float4*)(sw + (size_t)o * (IN_F * NB) + (k - IN_F));
  alignas(8) __hip_bfloat16 t[4];
  t[0] = __float2bfloat16(val.x);
  t[1] = __float2bfloat16(val.y);
  t[2] = __float2bfloat16(val.z);
  t[3] = __float2bfloat16(val.w);
  *(bf16x4*)(W + e) = *(const bf16x4*)t;
}

// C = A[4096,9216] @ W[1024,9216]^T.  128x128x32 MFMA tile, split-K over blockIdx.z.
// LDS layout: 8 groups of 16 rows; group g occupies [g*512, g*512+512) bf16, chunk
// order = MFMA fragment order (lane l holds row=l&15, kc=l>>4) -> staging writes
// (wave-uniform base + lane*16) land exactly where ds_read_b128 wants them, and the
// fragment read address is base + 16*lane: linear, bank-conflict-free.
__global__ __launch_bounds__(256) void gemm_kernel(const __hip_bfloat16* __restrict__ A,
                                                   const __hip_bfloat16* __restrict__ W,
                                                   float* __restrict__ dst,
                                                   const float* __restrict__ bias,
                                                   int kslice, int use_bias) {
  __shared__ __hip_bfloat16 lA[128 * 32];
  __shared__ __hip_bfloat16 lB[128 * 32];
  const int tid = threadIdx.x;
  const int wave = tid >> 6;
  const int lane = tid & 63;
  const int bm = blockIdx.x * 128;
  const int bn = blockIdx.y * 128;
  const int z = blockIdx.z;
  float* __restrict__ d = dst + (size_t)z * SLICE_ELEMS;
  const int kbeg = z * kslice;
  const int kend = kbeg + kslice;
  const int srow = lane & 15;       // staging: row within 16-row group
  const int skc = (lane >> 4) * 8;  // staging: k element offset (16B chunk)
  const int wm = (wave & 1) * 64;   // 2x2 wave grid -> 64x64 per wave
  const int wn = (wave >> 1) * 64;
  const int r = lane & 15;
  const int quad = lane >> 4;

  f32x4 acc[4][4];
#pragma unroll
  for (int a = 0; a < 4; ++a)
#pragma unroll
    for (int b = 0; b < 4; ++b) acc[a][b] = (f32x4){0.f, 0.f, 0.f, 0.f};

  for (int k0 = kbeg; k0 < kend; k0 += 32) {
#pragma unroll
    for (int h = 0; h < 2; ++h) {
      const int group = wave * 2 + h;
      const int row = group * 16 + srow;
      const __hip_bfloat16* ga = A + (size_t)(bm + row) * KDIM + k0 + skc;
      const __hip_bfloat16* gb = W + (size_t)(bn + row) * KDIM + k0 + skc;
      __builtin_amdgcn_global_load_lds((const __attribute__((address_space(1))) void*)ga,
                                       (__attribute__((address_space(3))) void*)(lA + group * 512),
                                       16, 0, 0);
      __builtin_amdgcn_global_load_lds((const __attribute__((address_space(1))) void*)gb,
                                       (__attribute__((address_space(3))) void*)(lB + group * 512),
                                       16, 0, 0);
    }
    __syncthreads();

    bf16x8 af[4], bfr[4];
#pragma unroll
    for (int t = 0; t < 4; ++t) {
      af[t] = *(const bf16x8*)(lA + ((wm >> 4) + t) * 512 + lane * 8);
      bfr[t] = *(const bf16x8*)(lB + ((wn >> 4) + t) * 512 + lane * 8);
    }
#pragma unroll
    for (int tm = 0; tm < 4; ++tm)
#pragma unroll
      for (int tn = 0; tn < 4; ++tn)
        acc[tm][tn] =
            __builtin_amdgcn_mfma_f32_16x16x32_bf16(af[tm], bfr[tn], acc[tm][tn], 0, 0, 0);
    __syncthreads();
  }

  // C/D map: col=lane&15, row=quad*4+reg (m89-verified).
#pragma unroll
  for (int tm = 0; tm < 4; ++tm) {
#pragma unroll
    for (int tn = 0; tn < 4; ++tn) {
      const int col = bn + wn + tn * 16 + r;
      const float bv = use_bias ? bias[col] : 0.0f;
#pragma unroll
      for (int reg = 0; reg < 4; ++reg) {
        const int rowi = bm + wm + tm * 16 + quad * 4 + reg;
        d[(size_t)rowi * OUT_F + col] = acc[tm][tn][reg] + bv;
      }
    }
  }
}

// out = bias + sum_s partial[s], float4 per thread.
__global__ void reduce_kernel(const float* __restrict__ P, const float* __restrict__ bias,
                              float* __restrict__ out, int S) {
  int v = blockIdx.x * 256 + threadIdx.x;
  int e = v * 4;
  int o = e & (OUT_F - 1);
  float4 acc = *(const float4*)(bias + o);
  for (int s = 0; s < S; ++s) {
    float4 p = *(const float4*)(P + (size_t)s * SLICE_ELEMS + e);
    acc.x += p.x;
    acc.y += p.y;
    acc.z += p.z;
    acc.w += p.w;
  }
  *(float4*)(out + e) = acc;
}

// Emergency fallback if ws is too small for A+W (fp32, slow but correct).
__global__ void kan_fallback(const float* __restrict__ x, const float* __restrict__ bw,
                             const float* __restrict__ bb, const float* __restrict__ sw,
                             float* __restrict__ out) {
  __shared__ float act[KDIM];
  int n = blockIdx.x;
  for (int i = threadIdx.x; i < IN_F; i += 256) {
    float xv = x[(size_t)n * IN_F + i];
    act[i] = xv / (1.0f + __expf(-xv));
    float b8[8];
    bspline8(xv, b8);
#pragma unroll
    for (int c = 0; c < 8; ++c) act[IN_F + i * 8 + c] = b8[c];
  }
  __syncthreads();
  for (int o = threadIdx.x; o < OUT_F; o += 256) {
    float s = bb[o];
    const float* wbp = bw + (size_t)o * IN_F;
    for (int k = 0; k < IN_F; ++k) s += act[k] * wbp[k];
    const float* wsp = sw + (size_t)o * (IN_F * NB);
    for (int k = 0; k < IN_F * NB; ++k) s += act[IN_F + k] * wsp[k];
    out[(size_t)n * OUT_F + o] = s;
  }
}

extern "C" void kernel_launch(void* const* d_in, const int* in_sizes, int n_in, void* d_out,
                              int out_size, void* d_ws, size_t ws_size, hipStream_t stream) {
  const float* x = (const float*)d_in[0];
  const float* bw = (const float*)d_in[1];
  const float* bb = (const float*)d_in[2];
  const float* sw = (const float*)d_in[3];
  float* out = (float*)d_out;

  const size_t needA = (size_t)NROWS * KDIM * 2;  // 75.5 MB (16B-aligned)
  const size_t needW = (size_t)OUT_F * KDIM * 2;  // 18.9 MB (16B-aligned)
  const size_t sliceB = (size_t)SLICE_ELEMS * 4;  // 16.8 MB
  if (ws_size < needA + needW) {
    kan_fallback<<<NROWS, 256, 0, stream>>>(x, bw, bb, sw, out);
    return;
  }
  __hip_bfloat16* A = (__hip_bfloat16*)d_ws;
  __hip_bfloat16* W = (__hip_bfloat16*)((char*)d_ws + needA);
  float* P = (float*)((char*)d_ws + needA + needW);
  const size_t avail = ws_size - needA - needW;
  int S = 1;
  if (avail >= 4 * sliceB)
    S = 4;  // 1024 blocks = 4 blocks/CU
  else if (avail >= 2 * sliceB)
    S = 2;

  prep_kernel<<<(NROWS * IN_F) / 256, 256, 0, stream>>>(x, A);
  wconv_kernel<<<(OUT_F * KDIM) / (4 * 256), 256, 0, stream>>>(bw, sw, W);
  if (S == 1) {
    gemm_kernel<<<dim3(NROWS / 128, OUT_F / 128, 1), 256, 0, stream>>>(A, W, out, bb, KDIM, 1);
  } else {
    gemm_kernel<<<dim3(NROWS / 128, OUT_F / 128, S), 256, 0, stream>>>(A, W, P, bb, KDIM / S, 0);
    reduce_kernel<<<SLICE_ELEMS / (4 * 256), 256, 0, stream>>>(P, bb, out, S);
  }
}